// Round 10
// baseline (30181.070 us; speedup 1.0000x reference)
//
#include <hip/hip_runtime.h>
#include <math.h>

#define TLEN 512
#define BSZ  64
#define EDIM 256
#define HDIM 256
#define GDIM 1024
#define KTAG 32

__device__ __forceinline__ float sigf(float x) { return 1.0f / (1.0f + expf(-x)); }

// ---------------------------------------------------------------------------
// Dual-direction GEMM over a time-chunk of C steps (C*64 rows).
// ---------------------------------------------------------------------------
template<int KDIM, bool GATHER>
__global__ __launch_bounds__(256)
void gemm_dual(const float* __restrict__ A, const int* __restrict__ idx,
               const float* __restrict__ Bf, const float* __restrict__ Bb,
               const float* __restrict__ b1f, const float* __restrict__ b2f,
               const float* __restrict__ b1b, const float* __restrict__ b2b,
               float* __restrict__ Cf, float* __restrict__ Cb,
               int t0f, int t0b, int r0f, int r0b)
{
    __shared__ __align__(16) float As[8][132];
    __shared__ __align__(16) float Bs[8][132];
    const int mt = blockIdx.x * 128;
    const int ng = blockIdx.y * 128;
    const bool isF = (ng < GDIM);
    const int nt = isF ? ng : (ng - GDIM);
    const float* Bw = isF ? Bf : Bb;
    const float* bias1 = isF ? b1f : b1b;
    const float* bias2 = isF ? b2f : b2b;
    float* C = isF ? Cf : Cb;
    const int t0 = isF ? t0f : t0b;
    const int r0 = isF ? r0f : r0b;

    const int tid = threadIdx.x;
    const int tx = tid & 15;
    const int ty = tid >> 4;
    const int srow = tid >> 1;
    const int skq = (tid & 1) * 4;

    const float* arow;
    if (GATHER) {
        int m = mt + srow;
        int t = t0 + (m >> 6);
        int b = m & 63;
        arow = A + (size_t)idx[b * TLEN + t] * (size_t)KDIM;
    } else {
        arow = A + (size_t)(r0 + mt + srow) * (size_t)KDIM;
    }
    const float* brow = Bw + (size_t)(nt + srow) * (size_t)KDIM;

    float acc[8][8];
    #pragma unroll
    for (int i = 0; i < 8; ++i)
        #pragma unroll
        for (int j = 0; j < 8; ++j) acc[i][j] = 0.0f;

    for (int k0 = 0; k0 < KDIM; k0 += 8) {
        float4 av = *(const float4*)(arow + k0 + skq);
        float4 bv = *(const float4*)(brow + k0 + skq);
        __syncthreads();
        As[skq + 0][srow] = av.x; As[skq + 1][srow] = av.y;
        As[skq + 2][srow] = av.z; As[skq + 3][srow] = av.w;
        Bs[skq + 0][srow] = bv.x; Bs[skq + 1][srow] = bv.y;
        Bs[skq + 2][srow] = bv.z; Bs[skq + 3][srow] = bv.w;
        __syncthreads();
        #pragma unroll
        for (int k = 0; k < 8; ++k) {
            float a[8], bb2[8];
            *(float4*)(a)       = *(const float4*)&As[k][ty * 8];
            *(float4*)(a + 4)   = *(const float4*)&As[k][ty * 8 + 4];
            *(float4*)(bb2)     = *(const float4*)&Bs[k][tx * 4];
            *(float4*)(bb2 + 4) = *(const float4*)&Bs[k][64 + tx * 4];
            #pragma unroll
            for (int i = 0; i < 8; ++i)
                #pragma unroll
                for (int j = 0; j < 8; ++j)
                    acc[i][j] = fmaf(a[i], bb2[j], acc[i][j]);
        }
    }

    float bs[8];
    #pragma unroll
    for (int j = 0; j < 4; ++j) bs[j] = bias1[nt + tx * 4 + j] + bias2[nt + tx * 4 + j];
    #pragma unroll
    for (int j = 4; j < 8; ++j) bs[j] = bias1[nt + 64 + tx * 4 + j - 4] + bias2[nt + 64 + tx * 4 + j - 4];
    #pragma unroll
    for (int i = 0; i < 8; ++i) {
        size_t row = (size_t)(mt + ty * 8 + i);
        float* cp0 = C + row * GDIM + nt + tx * 4;
        float* cp1 = C + row * GDIM + nt + 64 + tx * 4;
        *(float4*)cp0 = make_float4(acc[i][0] + bs[0], acc[i][1] + bs[1],
                                    acc[i][2] + bs[2], acc[i][3] + bs[3]);
        *(float4*)cp1 = make_float4(acc[i][4] + bs[4], acc[i][5] + bs[5],
                                    acc[i][6] + bs[6], acc[i][7] + bs[7]);
    }
}

// ---------------------------------------------------------------------------
// Cluster LSTM: 128 blocks x 512 threads; cluster cl = bid & 31 has 4 blocks
// rb = bid>>5. Block rb owns W rows for units [rb*64, rb*64+64) (256 rows),
// PINNED in VGPRs via asm "+v". Sync: per-(cl,rb) flag on its OWN 256B line.
// DEADLOCK FIX vs r9: signal store and sibling polls are separated by a
// __syncthreads() so the store cannot be exec-mask-serialized AFTER the spin
// (r9 hung: same-wave divergent branch ran the spin side first).
// ---------------------------------------------------------------------------
template<bool TOXBUF>
__global__ __launch_bounds__(512, 2)
void lstm_rec2(const float* __restrict__ gx_f, const float* __restrict__ gx_b,
               const float* __restrict__ Wf, const float* __restrict__ Wb,
               float* __restrict__ xout, float* __restrict__ hbuf,
               float* __restrict__ state,
               float* __restrict__ hx,           // [2][32][4][256]
               unsigned int* __restrict__ flags, // [32*4*64] padded
               int t0f, int t0b, int C, int init)
{
    const int bid = blockIdx.x;
    const int cl  = bid & 31;
    const int rb  = bid >> 5;          // 0..3 unit-block
    const int dir = cl >> 4;
    const int b0g = (cl & 15) * 4;     // first of 4 batch elements
    const float* gx = dir ? gx_b : gx_f;
    const float* W  = dir ? Wb : Wf;
    const int t0 = dir ? t0b : t0f;

    const int t  = threadIdx.x;
    const int rr = t & 255;            // row-in-block: gate g = rr>>6, unit = rr&63
    const int kh = t >> 8;             // k-half
    const int urow = ((rr >> 6) * 256) + rb * 64 + (rr & 63);  // W_hh row

    __shared__ __align__(16) float h_lds[4][256];
    __shared__ __align__(16) float ps[2][4][256];   // [kh][b][rr]
    __shared__ __align__(16) float gxs[4][256];     // [b][rr]

    // W slice -> registers, once; pin with asm so it cannot be re-loaded.
    float4 w[32];
    {
        const float4* wrow = (const float4*)(W + (size_t)urow * HDIM + kh * 128);
        #pragma unroll
        for (int i = 0; i < 32; ++i) w[i] = wrow[i];
    }
    #pragma unroll
    for (int i = 0; i < 32; ++i)
        asm volatile("" : "+v"(w[i].x), "+v"(w[i].y), "+v"(w[i].z), "+v"(w[i].w));

    float cc = 0.0f;
    for (int i = t; i < 4 * 256; i += 512) {
        int b = i >> 8, u = i & 255;
        h_lds[b][u] = init ? 0.0f
            : state[(((size_t)dir * BSZ + (b0g + b)) * 2) * HDIM + u];
    }
    if (t < 256) {
        int b = t >> 6, ug = rb * 64 + (t & 63);
        if (!init)
            cc = state[(((size_t)dir * BSZ + (b0g + b)) * 2) * HDIM + HDIM + ug];
    }
    __syncthreads();

    for (int s = 0; s < C; ++s) {
        const int tloc = dir ? (C - 1 - s) : s;
        // ---- prefetch gx: 1024 values, 2 per thread ----
        const int idx2 = t * 2;
        const int pb = idx2 >> 8;
        const int rem = idx2 & 255;
        const float* gxp = gx + ((size_t)tloc * BSZ + (b0g + pb)) * GDIM
                         + ((rem >> 6) * 256) + rb * 64 + (rem & 63);
        float2 gv = *(const float2*)gxp;
        // ---- FMA: own 256 rows x 4 batch, k-half in registers ----
        float a0 = 0.f, a1 = 0.f, a2 = 0.f, a3 = 0.f;
        #pragma unroll
        for (int i = 0; i < 32; ++i) {
            float4 h0 = *(const float4*)&h_lds[0][kh * 128 + i * 4];
            float4 h1 = *(const float4*)&h_lds[1][kh * 128 + i * 4];
            float4 h2 = *(const float4*)&h_lds[2][kh * 128 + i * 4];
            float4 h3 = *(const float4*)&h_lds[3][kh * 128 + i * 4];
            a0 = fmaf(w[i].x, h0.x, a0); a0 = fmaf(w[i].y, h0.y, a0);
            a0 = fmaf(w[i].z, h0.z, a0); a0 = fmaf(w[i].w, h0.w, a0);
            a1 = fmaf(w[i].x, h1.x, a1); a1 = fmaf(w[i].y, h1.y, a1);
            a1 = fmaf(w[i].z, h1.z, a1); a1 = fmaf(w[i].w, h1.w, a1);
            a2 = fmaf(w[i].x, h2.x, a2); a2 = fmaf(w[i].y, h2.y, a2);
            a2 = fmaf(w[i].z, h2.z, a2); a2 = fmaf(w[i].w, h2.w, a2);
            a3 = fmaf(w[i].x, h3.x, a3); a3 = fmaf(w[i].y, h3.y, a3);
            a3 = fmaf(w[i].z, h3.z, a3); a3 = fmaf(w[i].w, h3.w, a3);
        }
        ps[kh][0][rr] = a0; ps[kh][1][rr] = a1;
        ps[kh][2][rr] = a2; ps[kh][3][rr] = a3;
        gxs[pb][rem] = gv.x; gxs[pb][rem + 1] = gv.y;
        __syncthreads();
        // ---- gates + h for own 64 units x 4 batch ----
        if (t < 256) {
            const int b = t >> 6, u = t & 63;
            float pi = ps[0][b][u]       + ps[1][b][u]       + gxs[b][u];
            float pf = ps[0][b][64 + u]  + ps[1][b][64 + u]  + gxs[b][64 + u];
            float pg = ps[0][b][128 + u] + ps[1][b][128 + u] + gxs[b][128 + u];
            float po = ps[0][b][192 + u] + ps[1][b][192 + u] + gxs[b][192 + u];
            float iv = sigf(pi), fv = sigf(pf), gv2 = tanhf(pg), ov = sigf(po);
            cc = fv * cc + iv * gv2;
            float hv = ov * tanhf(cc);
            const int ug = rb * 64 + u;
            hx[(((size_t)(s & 1) * 32 + cl) * 4 + b) * 256 + ug] = hv;
            if (TOXBUF)
                xout[((size_t)(t0 + tloc) * BSZ + (b0g + b)) * 512 + dir * HDIM + ug] = hv;
            else
                hbuf[(((size_t)dir * C + tloc) * BSZ + (b0g + b)) * HDIM + ug] = hv;
            __threadfence();               // release own h writes (device scope)
        }
        __syncthreads();
        // ---- cluster barrier (deadlock-free ordering) ----
        if (t == 0)
            __hip_atomic_store(&flags[(cl * 4 + rb) * 64], (unsigned)(s + 1),
                               __ATOMIC_RELEASE, __HIP_MEMORY_SCOPE_AGENT);
        __syncthreads();                   // own flag is STORED before any poll
        if (t < 3) {
            const int sib = (rb + 1 + t) & 3;
            while (__hip_atomic_load(&flags[(cl * 4 + sib) * 64],
                                     __ATOMIC_ACQUIRE, __HIP_MEMORY_SCOPE_AGENT)
                   <= (unsigned)s)
                __builtin_amdgcn_s_sleep(2);
        }
        __syncthreads();
        __threadfence();                   // acquire before reading siblings' h
        for (int i = t; i < 4 * 256; i += 512) {
            int b = i >> 8, u = i & 255;
            h_lds[b][u] = hx[(((size_t)(s & 1) * 32 + cl) * 4 + b) * 256 + u];
        }
        __syncthreads();
    }
    if (t < 256) {
        int b = t >> 6, ug = rb * 64 + (t & 63);
        size_t sb = (((size_t)dir * BSZ + (b0g + b)) * 2) * HDIM;
        state[sb + ug] = h_lds[b][ug];
        state[sb + HDIM + ug] = cc;
    }
}

// ---------------------------------------------------------------------------
// Partial emissions from one chunk of layer-1 h (both dirs).
// ---------------------------------------------------------------------------
__global__ __launch_bounds__(256)
void emis_part(const float* __restrict__ hbuf, const float* __restrict__ Wo,
               float* __restrict__ em_f, float* __restrict__ em_b,
               int t0f, int t0b, int C)
{
    __shared__ float Ws[128][33];
    const int dir = blockIdx.y;
    const int tid = threadIdx.x;
    const int r = tid >> 5;
    const int kk = tid & 31;
    const int mloc = blockIdx.x * 8 + r;
    const float* hrow = hbuf + ((size_t)dir * C * BSZ + mloc) * HDIM;
    float* emo = dir ? em_b : em_f;
    const int t0 = dir ? t0b : t0f;
    float acc = 0.0f;
    for (int kc = 0; kc < HDIM; kc += 128) {
        __syncthreads();
        for (int i = tid; i < KTAG * 128; i += 256) {
            int wk = i >> 7;
            int k = i & 127;
            Ws[k][wk] = Wo[(size_t)wk * 512 + dir * HDIM + kc + k];
        }
        __syncthreads();
        #pragma unroll 8
        for (int k4 = 0; k4 < 32; ++k4) {
            float4 xv = *(const float4*)(hrow + kc + k4 * 4);
            acc = fmaf(xv.x, Ws[k4 * 4 + 0][kk], acc);
            acc = fmaf(xv.y, Ws[k4 * 4 + 1][kk], acc);
            acc = fmaf(xv.z, Ws[k4 * 4 + 2][kk], acc);
            acc = fmaf(xv.w, Ws[k4 * 4 + 3][kk], acc);
        }
    }
    const int tloc = mloc >> 6;
    const int b = mloc & 63;
    emo[(((size_t)(t0 + tloc)) * BSZ + b) * KTAG + kk] = acc;
}

// ---------------------------------------------------------------------------
// Viterbi: one block per batch element; em prefetch + LDS backpointers.
// ---------------------------------------------------------------------------
__global__ __launch_bounds__(64)
void viterbi(const float* __restrict__ em_f, const float* __restrict__ em_b,
             const float* __restrict__ bo,
             const float* __restrict__ st, const float* __restrict__ en,
             const float* __restrict__ tr, int* __restrict__ out)
{
    const int b = blockIdx.x;
    const int lane = threadIdx.x;
    __shared__ float s_tr[KTAG][KTAG + 1];
    __shared__ float s_sc[KTAG];
    __shared__ float s_fin[KTAG];
    __shared__ unsigned char s_bp[TLEN - 1][KTAG];
    for (int i = lane; i < KTAG * KTAG; i += 64)
        s_tr[i >> 5][i & 31] = tr[i];
    float eFn = 0.f, eBn = 0.f;
    if (lane < KTAG) {
        size_t e0 = (size_t)b * KTAG + lane;
        s_sc[lane] = st[lane] + em_f[e0] + em_b[e0] + bo[lane];
        size_t e1 = ((size_t)1 * BSZ + b) * KTAG + lane;
        eFn = em_f[e1]; eBn = em_b[e1];
    }
    __syncthreads();
    for (int t = 1; t < TLEN; ++t) {
        float ecF = eFn, ecB = eBn;
        if (t + 1 < TLEN && lane < KTAG) {
            size_t e2 = ((size_t)(t + 1) * BSZ + b) * KTAG + lane;
            eFn = em_f[e2]; eBn = em_b[e2];
        }
        float best = -3.0e38f;
        int arg = 0;
        if (lane < KTAG) {
            #pragma unroll
            for (int i = 0; i < KTAG; ++i) {
                float c = s_sc[i] + s_tr[i][lane];
                if (c > best) { best = c; arg = i; }
            }
        }
        __syncthreads();
        if (lane < KTAG) {
            s_sc[lane] = best + ecF + ecB + bo[lane];
            s_bp[t - 1][lane] = (unsigned char)arg;
        }
        __syncthreads();
    }
    if (lane < KTAG) s_fin[lane] = s_sc[lane] + en[lane];
    __syncthreads();
    if (lane == 0) {
        int tag = 0;
        float bv = s_fin[0];
        for (int i = 1; i < KTAG; ++i)
            if (s_fin[i] > bv) { bv = s_fin[i]; tag = i; }
        out[(size_t)b * TLEN + (TLEN - 1)] = tag;
        for (int t = TLEN - 2; t >= 0; --t) {
            tag = s_bp[t][tag];
            out[(size_t)b * TLEN + t] = tag;
        }
    }
}

// ---------------------------------------------------------------------------
extern "C" void kernel_launch(void* const* d_in, const int* in_sizes, int n_in,
                              void* d_out, int out_size, void* d_ws, size_t ws_size,
                              hipStream_t stream)
{
    (void)in_sizes; (void)n_in; (void)out_size;
    const int*   inputs     = (const int*)d_in[0];
    const float* emb        = (const float*)d_in[1];
    const float* W_ih_l0_f  = (const float*)d_in[2];
    const float* W_hh_l0_f  = (const float*)d_in[3];
    const float* b_ih_l0_f  = (const float*)d_in[4];
    const float* b_hh_l0_f  = (const float*)d_in[5];
    const float* W_ih_l0_b  = (const float*)d_in[6];
    const float* W_hh_l0_b  = (const float*)d_in[7];
    const float* b_ih_l0_b  = (const float*)d_in[8];
    const float* b_hh_l0_b  = (const float*)d_in[9];
    const float* W_ih_l1_f  = (const float*)d_in[10];
    const float* W_hh_l1_f  = (const float*)d_in[11];
    const float* b_ih_l1_f  = (const float*)d_in[12];
    const float* b_hh_l1_f  = (const float*)d_in[13];
    const float* W_ih_l1_b  = (const float*)d_in[14];
    const float* W_hh_l1_b  = (const float*)d_in[15];
    const float* b_ih_l1_b  = (const float*)d_in[16];
    const float* b_hh_l1_b  = (const float*)d_in[17];
    const float* W_out      = (const float*)d_in[18];
    const float* b_out      = (const float*)d_in[19];
    const float* start_tr   = (const float*)d_in[20];
    const float* end_tr     = (const float*)d_in[21];
    const float* trans      = (const float*)d_in[22];

    // ws: xbuf 64MB | gx_f C*256KB | gx_b C*256KB | hbuf C*128KB |
    //     em_f 4MB | em_b 4MB | state 512KB | hx 256KB | flags 32KB
    const size_t XBUF = 67108864;
    const size_t TAIL = 4194304ull * 2 + 524288 + 262144 + 32768;
    int C = 16;
    for (int cand = TLEN; cand >= 16; cand >>= 1) {
        size_t need = XBUF + (size_t)cand * (524288 + 131072) + TAIL;
        if (need <= ws_size) { C = cand; break; }
    }
    char* ws = (char*)d_ws;
    float* xbuf = (float*)(ws);
    float* gx_f = (float*)(ws + XBUF);
    float* gx_b = (float*)(ws + XBUF + (size_t)C * 262144);
    float* hbuf = (float*)(ws + XBUF + (size_t)C * 524288);
    char*  tail = ws + XBUF + (size_t)C * (524288 + 131072);
    float* em_f = (float*)(tail);
    float* em_b = (float*)(tail + 4194304);
    float* state = (float*)(tail + 2 * 4194304);
    float* hx    = (float*)(tail + 2 * 4194304 + 524288);
    unsigned int* flags = (unsigned int*)(tail + 2 * 4194304 + 524288 + 262144);
    int* outi = (int*)d_out;

    const int nc = TLEN / C;
    dim3 gg(C / 2, 16);

    // ----- layer 0 -----
    for (int c = 0; c < nc; ++c) {
        int t0f = c * C;
        int t0b = TLEN - (c + 1) * C;
        gemm_dual<EDIM, true><<<gg, 256, 0, stream>>>(
            emb, inputs, W_ih_l0_f, W_ih_l0_b,
            b_ih_l0_f, b_hh_l0_f, b_ih_l0_b, b_hh_l0_b,
            gx_f, gx_b, t0f, t0b, 0, 0);
        hipMemsetAsync(flags, 0, 32768, stream);
        lstm_rec2<true><<<128, 512, 0, stream>>>(
            gx_f, gx_b, W_hh_l0_f, W_hh_l0_b, xbuf, nullptr, state,
            hx, flags, t0f, t0b, C, c == 0 ? 1 : 0);
    }
    // ----- layer 1 ----- (xbuf READ-ONLY; h -> hbuf -> em parts)
    for (int c = 0; c < nc; ++c) {
        int t0f = c * C;
        int t0b = TLEN - (c + 1) * C;
        gemm_dual<512, false><<<gg, 256, 0, stream>>>(
            xbuf, nullptr, W_ih_l1_f, W_ih_l1_b,
            b_ih_l1_f, b_hh_l1_f, b_ih_l1_b, b_hh_l1_b,
            gx_f, gx_b, t0f, t0b, t0f * BSZ, t0b * BSZ);
        hipMemsetAsync(flags, 0, 32768, stream);
        lstm_rec2<false><<<128, 512, 0, stream>>>(
            gx_f, gx_b, W_hh_l1_f, W_hh_l1_b, nullptr, hbuf, state,
            hx, flags, t0f, t0b, C, c == 0 ? 1 : 0);
        dim3 ge(C * 8, 2);
        emis_part<<<ge, 256, 0, stream>>>(hbuf, W_out, em_f, em_b, t0f, t0b, C);
    }

    viterbi<<<64, 64, 0, stream>>>(em_f, em_b, b_out, start_tr, end_tr, trans,
                                   outi);
}

// Round 11
// 6056.083 us; speedup vs baseline: 4.9836x; 4.9836x over previous
//
#include <hip/hip_runtime.h>
#include <math.h>

#define TLEN 512
#define BSZ  64
#define EDIM 256
#define HDIM 256
#define GDIM 1024
#define KTAG 32

__device__ __forceinline__ float sigf(float x) { return 1.0f / (1.0f + expf(-x)); }

// ---------------------------------------------------------------------------
// Dual-direction GEMM over a time-chunk of C steps (C*64 rows).
// ---------------------------------------------------------------------------
template<int KDIM, bool GATHER>
__global__ __launch_bounds__(256)
void gemm_dual(const float* __restrict__ A, const int* __restrict__ idx,
               const float* __restrict__ Bf, const float* __restrict__ Bb,
               const float* __restrict__ b1f, const float* __restrict__ b2f,
               const float* __restrict__ b1b, const float* __restrict__ b2b,
               float* __restrict__ Cf, float* __restrict__ Cb,
               int t0f, int t0b, int r0f, int r0b)
{
    __shared__ __align__(16) float As[8][132];
    __shared__ __align__(16) float Bs[8][132];
    const int mt = blockIdx.x * 128;
    const int ng = blockIdx.y * 128;
    const bool isF = (ng < GDIM);
    const int nt = isF ? ng : (ng - GDIM);
    const float* Bw = isF ? Bf : Bb;
    const float* bias1 = isF ? b1f : b1b;
    const float* bias2 = isF ? b2f : b2b;
    float* C = isF ? Cf : Cb;
    const int t0 = isF ? t0f : t0b;
    const int r0 = isF ? r0f : r0b;

    const int tid = threadIdx.x;
    const int tx = tid & 15;
    const int ty = tid >> 4;
    const int srow = tid >> 1;
    const int skq = (tid & 1) * 4;

    const float* arow;
    if (GATHER) {
        int m = mt + srow;
        int t = t0 + (m >> 6);
        int b = m & 63;
        arow = A + (size_t)idx[b * TLEN + t] * (size_t)KDIM;
    } else {
        arow = A + (size_t)(r0 + mt + srow) * (size_t)KDIM;
    }
    const float* brow = Bw + (size_t)(nt + srow) * (size_t)KDIM;

    float acc[8][8];
    #pragma unroll
    for (int i = 0; i < 8; ++i)
        #pragma unroll
        for (int j = 0; j < 8; ++j) acc[i][j] = 0.0f;

    for (int k0 = 0; k0 < KDIM; k0 += 8) {
        float4 av = *(const float4*)(arow + k0 + skq);
        float4 bv = *(const float4*)(brow + k0 + skq);
        __syncthreads();
        As[skq + 0][srow] = av.x; As[skq + 1][srow] = av.y;
        As[skq + 2][srow] = av.z; As[skq + 3][srow] = av.w;
        Bs[skq + 0][srow] = bv.x; Bs[skq + 1][srow] = bv.y;
        Bs[skq + 2][srow] = bv.z; Bs[skq + 3][srow] = bv.w;
        __syncthreads();
        #pragma unroll
        for (int k = 0; k < 8; ++k) {
            float a[8], bb2[8];
            *(float4*)(a)       = *(const float4*)&As[k][ty * 8];
            *(float4*)(a + 4)   = *(const float4*)&As[k][ty * 8 + 4];
            *(float4*)(bb2)     = *(const float4*)&Bs[k][tx * 4];
            *(float4*)(bb2 + 4) = *(const float4*)&Bs[k][64 + tx * 4];
            #pragma unroll
            for (int i = 0; i < 8; ++i)
                #pragma unroll
                for (int j = 0; j < 8; ++j)
                    acc[i][j] = fmaf(a[i], bb2[j], acc[i][j]);
        }
    }

    float bs[8];
    #pragma unroll
    for (int j = 0; j < 4; ++j) bs[j] = bias1[nt + tx * 4 + j] + bias2[nt + tx * 4 + j];
    #pragma unroll
    for (int j = 4; j < 8; ++j) bs[j] = bias1[nt + 64 + tx * 4 + j - 4] + bias2[nt + 64 + tx * 4 + j - 4];
    #pragma unroll
    for (int i = 0; i < 8; ++i) {
        size_t row = (size_t)(mt + ty * 8 + i);
        float* cp0 = C + row * GDIM + nt + tx * 4;
        float* cp1 = C + row * GDIM + nt + 64 + tx * 4;
        *(float4*)cp0 = make_float4(acc[i][0] + bs[0], acc[i][1] + bs[1],
                                    acc[i][2] + bs[2], acc[i][3] + bs[3]);
        *(float4*)cp1 = make_float4(acc[i][4] + bs[4], acc[i][5] + bs[5],
                                    acc[i][6] + bs[6], acc[i][7] + bs[7]);
    }
}

// ---------------------------------------------------------------------------
// Cluster LSTM: 128 blocks x 512 threads; cluster cl = bid & 31 has 4 blocks
// rb = bid>>5. Block rb owns W rows for units [rb*64, rb*64+64) (256 rows),
// held in the register file (asm-pinned). Cross-block exchange uses ONLY
// relaxed agent-scope atomics (bypass the non-coherent L1/L2 -> no
// buffer_inv / buffer_wbl2 per step, which was r10's 13us/step cost).
// Ordering: per-wave s_waitcnt vmcnt(0) after hx stores -> barrier -> flag
// store (relaxed) -> sibling polls (relaxed) -> barrier -> hx loads.
// ---------------------------------------------------------------------------
template<bool TOXBUF>
__global__ __launch_bounds__(512, 2)
void lstm_rec2(const float* __restrict__ gx_f, const float* __restrict__ gx_b,
               const float* __restrict__ Wf, const float* __restrict__ Wb,
               float* __restrict__ xout, float* __restrict__ hbuf,
               float* __restrict__ state,
               float* __restrict__ hx,           // [2][32][4][256]
               unsigned int* __restrict__ flags, // [32*4*64] padded
               int t0f, int t0b, int C, int init)
{
    const int bid = blockIdx.x;
    const int cl  = bid & 31;
    const int rb  = bid >> 5;          // 0..3 unit-block
    const int dir = cl >> 4;
    const int b0g = (cl & 15) * 4;     // first of 4 batch elements
    const float* gx = dir ? gx_b : gx_f;
    const float* W  = dir ? Wb : Wf;
    const int t0 = dir ? t0b : t0f;

    const int t  = threadIdx.x;
    const int rr = t & 255;            // row-in-block: gate g = rr>>6, unit = rr&63
    const int kh = t >> 8;             // k-half
    const int urow = ((rr >> 6) * 256) + rb * 64 + (rr & 63);  // W_hh row

    __shared__ __align__(16) float h_lds[4][256];
    __shared__ __align__(16) float ps[2][4][256];   // [kh][b][rr]
    __shared__ __align__(16) float gxs[4][256];     // [b][rr]

    // W slice -> registers, once; pin with asm so it cannot be re-loaded.
    float4 w[32];
    {
        const float4* wrow = (const float4*)(W + (size_t)urow * HDIM + kh * 128);
        #pragma unroll
        for (int i = 0; i < 32; ++i) w[i] = wrow[i];
    }
    #pragma unroll
    for (int i = 0; i < 32; ++i)
        asm volatile("" : "+v"(w[i].x), "+v"(w[i].y), "+v"(w[i].z), "+v"(w[i].w));

    float cc = 0.0f;
    for (int i = t; i < 4 * 256; i += 512) {
        int b = i >> 8, u = i & 255;
        h_lds[b][u] = init ? 0.0f
            : state[(((size_t)dir * BSZ + (b0g + b)) * 2) * HDIM + u];
    }
    if (t < 256) {
        int b = t >> 6, ug = rb * 64 + (t & 63);
        if (!init)
            cc = state[(((size_t)dir * BSZ + (b0g + b)) * 2) * HDIM + HDIM + ug];
    }
    __syncthreads();

    for (int s = 0; s < C; ++s) {
        const int tloc = dir ? (C - 1 - s) : s;
        // ---- prefetch gx: 1024 values, 2 per thread ----
        const int idx2 = t * 2;
        const int pb = idx2 >> 8;
        const int rem = idx2 & 255;
        const float* gxp = gx + ((size_t)tloc * BSZ + (b0g + pb)) * GDIM
                         + ((rem >> 6) * 256) + rb * 64 + (rem & 63);
        float2 gv = *(const float2*)gxp;
        // ---- FMA: own 256 rows x 4 batch, k-half in registers ----
        float a0 = 0.f, a1 = 0.f, a2 = 0.f, a3 = 0.f;
        #pragma unroll
        for (int i = 0; i < 32; ++i) {
            float4 h0 = *(const float4*)&h_lds[0][kh * 128 + i * 4];
            float4 h1 = *(const float4*)&h_lds[1][kh * 128 + i * 4];
            float4 h2 = *(const float4*)&h_lds[2][kh * 128 + i * 4];
            float4 h3 = *(const float4*)&h_lds[3][kh * 128 + i * 4];
            a0 = fmaf(w[i].x, h0.x, a0); a0 = fmaf(w[i].y, h0.y, a0);
            a0 = fmaf(w[i].z, h0.z, a0); a0 = fmaf(w[i].w, h0.w, a0);
            a1 = fmaf(w[i].x, h1.x, a1); a1 = fmaf(w[i].y, h1.y, a1);
            a1 = fmaf(w[i].z, h1.z, a1); a1 = fmaf(w[i].w, h1.w, a1);
            a2 = fmaf(w[i].x, h2.x, a2); a2 = fmaf(w[i].y, h2.y, a2);
            a2 = fmaf(w[i].z, h2.z, a2); a2 = fmaf(w[i].w, h2.w, a2);
            a3 = fmaf(w[i].x, h3.x, a3); a3 = fmaf(w[i].y, h3.y, a3);
            a3 = fmaf(w[i].z, h3.z, a3); a3 = fmaf(w[i].w, h3.w, a3);
        }
        ps[kh][0][rr] = a0; ps[kh][1][rr] = a1;
        ps[kh][2][rr] = a2; ps[kh][3][rr] = a3;
        gxs[pb][rem] = gv.x; gxs[pb][rem + 1] = gv.y;
        __syncthreads();
        // ---- gates + h for own 64 units x 4 batch ----
        if (t < 256) {
            const int b = t >> 6, u = t & 63;
            float pi = ps[0][b][u]       + ps[1][b][u]       + gxs[b][u];
            float pf = ps[0][b][64 + u]  + ps[1][b][64 + u]  + gxs[b][64 + u];
            float pg = ps[0][b][128 + u] + ps[1][b][128 + u] + gxs[b][128 + u];
            float po = ps[0][b][192 + u] + ps[1][b][192 + u] + gxs[b][192 + u];
            float iv = sigf(pi), fv = sigf(pf), gv2 = tanhf(pg), ov = sigf(po);
            cc = fv * cc + iv * gv2;
            float hv = ov * tanhf(cc);
            const int ug = rb * 64 + u;
            h_lds[b][ug] = hv;                       // own slice -> LDS directly
            if (TOXBUF)
                xout[((size_t)(t0 + tloc) * BSZ + (b0g + b)) * 512 + dir * HDIM + ug] = hv;
            else
                hbuf[(((size_t)dir * C + tloc) * BSZ + (b0g + b)) * HDIM + ug] = hv;
            // publish to siblings: bypassing store to the coherent point
            __hip_atomic_store(&hx[(((size_t)(s & 1) * 32 + cl) * 4 + b) * 256 + ug],
                               hv, __ATOMIC_RELAXED, __HIP_MEMORY_SCOPE_AGENT);
            // per-wave completion wait: hx stores are at the coherent point
            asm volatile("s_waitcnt vmcnt(0)" ::: "memory");
        }
        __syncthreads();                  // all 4 storing waves done
        if (t == 0)
            __hip_atomic_store(&flags[(cl * 4 + rb) * 64], (unsigned)(s + 1),
                               __ATOMIC_RELAXED, __HIP_MEMORY_SCOPE_AGENT);
        __syncthreads();                  // own flag stored before any poll
        if (t < 3) {
            const int sib = (rb + 1 + t) & 3;
            while (__hip_atomic_load(&flags[(cl * 4 + sib) * 64],
                                     __ATOMIC_RELAXED, __HIP_MEMORY_SCOPE_AGENT)
                   <= (unsigned)s)
                __builtin_amdgcn_s_sleep(1);
        }
        __syncthreads();
        // siblings' h (768 values) via bypassing loads; own slice already in LDS
        for (int i = t; i < 4 * 256; i += 512) {
            int b = i >> 8, u = i & 255;
            if ((u >> 6) != rb)
                h_lds[b][u] = __hip_atomic_load(
                    &hx[(((size_t)(s & 1) * 32 + cl) * 4 + b) * 256 + u],
                    __ATOMIC_RELAXED, __HIP_MEMORY_SCOPE_AGENT);
        }
        __syncthreads();
    }
    if (t < 256) {
        int b = t >> 6, ug = rb * 64 + (t & 63);
        size_t sb = (((size_t)dir * BSZ + (b0g + b)) * 2) * HDIM;
        state[sb + ug] = h_lds[b][ug];
        state[sb + HDIM + ug] = cc;
    }
}

// ---------------------------------------------------------------------------
// Partial emissions from one chunk of layer-1 h (both dirs).
// ---------------------------------------------------------------------------
__global__ __launch_bounds__(256)
void emis_part(const float* __restrict__ hbuf, const float* __restrict__ Wo,
               float* __restrict__ em_f, float* __restrict__ em_b,
               int t0f, int t0b, int C)
{
    __shared__ float Ws[128][33];
    const int dir = blockIdx.y;
    const int tid = threadIdx.x;
    const int r = tid >> 5;
    const int kk = tid & 31;
    const int mloc = blockIdx.x * 8 + r;
    const float* hrow = hbuf + ((size_t)dir * C * BSZ + mloc) * HDIM;
    float* emo = dir ? em_b : em_f;
    const int t0 = dir ? t0b : t0f;
    float acc = 0.0f;
    for (int kc = 0; kc < HDIM; kc += 128) {
        __syncthreads();
        for (int i = tid; i < KTAG * 128; i += 256) {
            int wk = i >> 7;
            int k = i & 127;
            Ws[k][wk] = Wo[(size_t)wk * 512 + dir * HDIM + kc + k];
        }
        __syncthreads();
        #pragma unroll 8
        for (int k4 = 0; k4 < 32; ++k4) {
            float4 xv = *(const float4*)(hrow + kc + k4 * 4);
            acc = fmaf(xv.x, Ws[k4 * 4 + 0][kk], acc);
            acc = fmaf(xv.y, Ws[k4 * 4 + 1][kk], acc);
            acc = fmaf(xv.z, Ws[k4 * 4 + 2][kk], acc);
            acc = fmaf(xv.w, Ws[k4 * 4 + 3][kk], acc);
        }
    }
    const int tloc = mloc >> 6;
    const int b = mloc & 63;
    emo[(((size_t)(t0 + tloc)) * BSZ + b) * KTAG + kk] = acc;
}

// ---------------------------------------------------------------------------
// Viterbi: one block per batch element; em prefetch + LDS backpointers.
// ---------------------------------------------------------------------------
__global__ __launch_bounds__(64)
void viterbi(const float* __restrict__ em_f, const float* __restrict__ em_b,
             const float* __restrict__ bo,
             const float* __restrict__ st, const float* __restrict__ en,
             const float* __restrict__ tr, int* __restrict__ out)
{
    const int b = blockIdx.x;
    const int lane = threadIdx.x;
    __shared__ float s_tr[KTAG][KTAG + 1];
    __shared__ float s_sc[KTAG];
    __shared__ float s_fin[KTAG];
    __shared__ unsigned char s_bp[TLEN - 1][KTAG];
    for (int i = lane; i < KTAG * KTAG; i += 64)
        s_tr[i >> 5][i & 31] = tr[i];
    float eFn = 0.f, eBn = 0.f;
    if (lane < KTAG) {
        size_t e0 = (size_t)b * KTAG + lane;
        s_sc[lane] = st[lane] + em_f[e0] + em_b[e0] + bo[lane];
        size_t e1 = ((size_t)1 * BSZ + b) * KTAG + lane;
        eFn = em_f[e1]; eBn = em_b[e1];
    }
    __syncthreads();
    for (int t = 1; t < TLEN; ++t) {
        float ecF = eFn, ecB = eBn;
        if (t + 1 < TLEN && lane < KTAG) {
            size_t e2 = ((size_t)(t + 1) * BSZ + b) * KTAG + lane;
            eFn = em_f[e2]; eBn = em_b[e2];
        }
        float best = -3.0e38f;
        int arg = 0;
        if (lane < KTAG) {
            #pragma unroll
            for (int i = 0; i < KTAG; ++i) {
                float c = s_sc[i] + s_tr[i][lane];
                if (c > best) { best = c; arg = i; }
            }
        }
        __syncthreads();
        if (lane < KTAG) {
            s_sc[lane] = best + ecF + ecB + bo[lane];
            s_bp[t - 1][lane] = (unsigned char)arg;
        }
        __syncthreads();
    }
    if (lane < KTAG) s_fin[lane] = s_sc[lane] + en[lane];
    __syncthreads();
    if (lane == 0) {
        int tag = 0;
        float bv = s_fin[0];
        for (int i = 1; i < KTAG; ++i)
            if (s_fin[i] > bv) { bv = s_fin[i]; tag = i; }
        out[(size_t)b * TLEN + (TLEN - 1)] = tag;
        for (int t = TLEN - 2; t >= 0; --t) {
            tag = s_bp[t][tag];
            out[(size_t)b * TLEN + t] = tag;
        }
    }
}

// ---------------------------------------------------------------------------
extern "C" void kernel_launch(void* const* d_in, const int* in_sizes, int n_in,
                              void* d_out, int out_size, void* d_ws, size_t ws_size,
                              hipStream_t stream)
{
    (void)in_sizes; (void)n_in; (void)out_size;
    const int*   inputs     = (const int*)d_in[0];
    const float* emb        = (const float*)d_in[1];
    const float* W_ih_l0_f  = (const float*)d_in[2];
    const float* W_hh_l0_f  = (const float*)d_in[3];
    const float* b_ih_l0_f  = (const float*)d_in[4];
    const float* b_hh_l0_f  = (const float*)d_in[5];
    const float* W_ih_l0_b  = (const float*)d_in[6];
    const float* W_hh_l0_b  = (const float*)d_in[7];
    const float* b_ih_l0_b  = (const float*)d_in[8];
    const float* b_hh_l0_b  = (const float*)d_in[9];
    const float* W_ih_l1_f  = (const float*)d_in[10];
    const float* W_hh_l1_f  = (const float*)d_in[11];
    const float* b_ih_l1_f  = (const float*)d_in[12];
    const float* b_hh_l1_f  = (const float*)d_in[13];
    const float* W_ih_l1_b  = (const float*)d_in[14];
    const float* W_hh_l1_b  = (const float*)d_in[15];
    const float* b_ih_l1_b  = (const float*)d_in[16];
    const float* b_hh_l1_b  = (const float*)d_in[17];
    const float* W_out      = (const float*)d_in[18];
    const float* b_out      = (const float*)d_in[19];
    const float* start_tr   = (const float*)d_in[20];
    const float* end_tr     = (const float*)d_in[21];
    const float* trans      = (const float*)d_in[22];

    // ws: xbuf 64MB | gx_f C*256KB | gx_b C*256KB | hbuf C*128KB |
    //     em_f 4MB | em_b 4MB | state 512KB | hx 256KB | flags 32KB
    const size_t XBUF = 67108864;
    const size_t TAIL = 4194304ull * 2 + 524288 + 262144 + 32768;
    int C = 16;
    for (int cand = TLEN; cand >= 16; cand >>= 1) {
        size_t need = XBUF + (size_t)cand * (524288 + 131072) + TAIL;
        if (need <= ws_size) { C = cand; break; }
    }
    char* ws = (char*)d_ws;
    float* xbuf = (float*)(ws);
    float* gx_f = (float*)(ws + XBUF);
    float* gx_b = (float*)(ws + XBUF + (size_t)C * 262144);
    float* hbuf = (float*)(ws + XBUF + (size_t)C * 524288);
    char*  tail = ws + XBUF + (size_t)C * (524288 + 131072);
    float* em_f = (float*)(tail);
    float* em_b = (float*)(tail + 4194304);
    float* state = (float*)(tail + 2 * 4194304);
    float* hx    = (float*)(tail + 2 * 4194304 + 524288);
    unsigned int* flags = (unsigned int*)(tail + 2 * 4194304 + 524288 + 262144);
    int* outi = (int*)d_out;

    const int nc = TLEN / C;
    dim3 gg(C / 2, 16);

    // ----- layer 0 -----
    for (int c = 0; c < nc; ++c) {
        int t0f = c * C;
        int t0b = TLEN - (c + 1) * C;
        gemm_dual<EDIM, true><<<gg, 256, 0, stream>>>(
            emb, inputs, W_ih_l0_f, W_ih_l0_b,
            b_ih_l0_f, b_hh_l0_f, b_ih_l0_b, b_hh_l0_b,
            gx_f, gx_b, t0f, t0b, 0, 0);
        hipMemsetAsync(flags, 0, 32768, stream);
        lstm_rec2<true><<<128, 512, 0, stream>>>(
            gx_f, gx_b, W_hh_l0_f, W_hh_l0_b, xbuf, nullptr, state,
            hx, flags, t0f, t0b, C, c == 0 ? 1 : 0);
    }
    // ----- layer 1 ----- (xbuf READ-ONLY; h -> hbuf -> em parts)
    for (int c = 0; c < nc; ++c) {
        int t0f = c * C;
        int t0b = TLEN - (c + 1) * C;
        gemm_dual<512, false><<<gg, 256, 0, stream>>>(
            xbuf, nullptr, W_ih_l1_f, W_ih_l1_b,
            b_ih_l1_f, b_hh_l1_f, b_ih_l1_b, b_hh_l1_b,
            gx_f, gx_b, t0f, t0b, t0f * BSZ, t0b * BSZ);
        hipMemsetAsync(flags, 0, 32768, stream);
        lstm_rec2<false><<<128, 512, 0, stream>>>(
            gx_f, gx_b, W_hh_l1_f, W_hh_l1_b, nullptr, hbuf, state,
            hx, flags, t0f, t0b, C, c == 0 ? 1 : 0);
        dim3 ge(C * 8, 2);
        emis_part<<<ge, 256, 0, stream>>>(hbuf, W_out, em_f, em_b, t0f, t0b, C);
    }

    viterbi<<<64, 64, 0, stream>>>(em_f, em_b, b_out, start_tr, end_tr, trans,
                                   outi);
}